// Round 3
// baseline (10938.656 us; speedup 1.0000x reference)
//
#include <hip/hip_runtime.h>

#define BB 64
#define PP 196
#define EE 2048
#define LL 32
#define VV 10000
#define EMBD 512
#define DECD 512
#define ATTD 512
#define TT 31

// ---------------- setup kernels ----------------

extern "C" __global__ void k_sort(const int* __restrict__ cap_len,
                                  int* __restrict__ sort_ind,
                                  int* __restrict__ dlens) {
  int i = threadIdx.x;
  if (i >= BB) return;
  int li = cap_len[i];
  int rank = 0;
  for (int j = 0; j < BB; ++j) {
    int lj = cap_len[j];
    rank += (lj > li) || (lj == li && j < i);   // stable argsort(-lens)
  }
  sort_ind[rank] = i;
  dlens[rank] = li - 1;
}

__global__ __launch_bounds__(256) void k_mean(const float* __restrict__ enc,
                                              const int* __restrict__ sort_ind,
                                              float* __restrict__ mean_enc) {
  int b = blockIdx.x >> 3;                       // E/256 = 8 blocks per b
  int e = ((blockIdx.x & 7) << 8) + threadIdx.x;
  int sb = sort_ind[b];
  const float* base = enc + (size_t)sb * PP * EE + e;
  float s = 0.f;
#pragma unroll 4
  for (int p = 0; p < PP; ++p) s += base[(size_t)p * EE];
  mean_enc[b * EE + e] = s * (1.0f / PP);
}

__global__ __launch_bounds__(256) void k_h0c0(const float* __restrict__ mean_enc,
                                              const float* __restrict__ Whi,
                                              const float* __restrict__ bhi,
                                              const float* __restrict__ Wci,
                                              const float* __restrict__ bci,
                                              float* __restrict__ h0,
                                              float* __restrict__ c0) {
  int idx = blockIdx.x * 256 + threadIdx.x;      // 2*B*DEC = 65536
  int which = idx >> 15;
  int r = idx & 32767;
  int b = r >> 9, j = r & 511;
  const float* W = which ? Wci : Whi;
  float acc = which ? bci[j] : bhi[j];
  const float* m = mean_enc + b * EE;
#pragma unroll 4
  for (int k = 0; k < EE; ++k) acc = fmaf(m[k], W[k * DECD + j], acc);
  if (which) c0[r] = acc; else h0[r] = acc;
}

// att1 = enc[sorted] @ We + be   (M=B*P=12544, K=2048, N=512), fp32
// 8 rows per block to amortize We reads; 2 cols per thread.
__global__ __launch_bounds__(256) void k_att1(const float* __restrict__ enc,
                                              const int* __restrict__ sort_ind,
                                              const float* __restrict__ We,
                                              const float* __restrict__ be,
                                              float* __restrict__ att1) {
  int row0 = blockIdx.x * 8;
  int j = threadIdx.x;
  const float* ap[8];
#pragma unroll
  for (int m = 0; m < 8; ++m) {
    int row = row0 + m;
    int b = row / PP, p = row - b * PP;
    int sb = sort_ind[b];
    ap[m] = enc + ((size_t)sb * PP + p) * EE;
  }
  float acc0[8], acc1[8];
  float be0 = be[j], be1 = be[j + 256];
#pragma unroll
  for (int m = 0; m < 8; ++m) { acc0[m] = be0; acc1[m] = be1; }
#pragma unroll 2
  for (int k = 0; k < EE; ++k) {
    float w0 = We[k * ATTD + j];
    float w1 = We[k * ATTD + j + 256];
#pragma unroll
    for (int m = 0; m < 8; ++m) {
      float a = ap[m][k];
      acc0[m] = fmaf(a, w0, acc0[m]);
      acc1[m] = fmaf(a, w1, acc1[m]);
    }
  }
#pragma unroll
  for (int m = 0; m < 8; ++m) {
    att1[(size_t)(row0 + m) * ATTD + j] = acc0[m];
    att1[(size_t)(row0 + m) * ATTD + j + 256] = acc1[m];
  }
}

// ---------------- per-step kernels ----------------

// att2 = h@Wd+bd ; gateLin = h@Wb+bb ; plus copies emb_t -> xfull[:,0:512],
// h -> xfull[:,2560:3072].  8 batch rows per dot-thread (uniform h loads).
__global__ __launch_bounds__(256) void k_hproj(const float* __restrict__ h_in,
                                               const float* __restrict__ Wd,
                                               const float* __restrict__ bd,
                                               const float* __restrict__ Wb,
                                               const float* __restrict__ bb,
                                               const float* __restrict__ emb,
                                               const int* __restrict__ caps,
                                               const int* __restrict__ sort_ind,
                                               float* __restrict__ att2,
                                               float* __restrict__ gateLin,
                                               float* __restrict__ xfull,
                                               int t) {
  int idx = blockIdx.x * 256 + threadIdx.x;
  if (idx < 2560 * 8) {
    int col = idx % 2560;
    int b0 = (idx / 2560) * 8;
    const float* hp = h_in + b0 * DECD;
    float acc[8];
    if (col < ATTD) {
      float bv = bd[col];
#pragma unroll
      for (int m = 0; m < 8; ++m) acc[m] = bv;
#pragma unroll 4
      for (int k = 0; k < DECD; ++k) {
        float w = Wd[k * ATTD + col];
#pragma unroll
        for (int m = 0; m < 8; ++m) acc[m] = fmaf(hp[m * DECD + k], w, acc[m]);
      }
#pragma unroll
      for (int m = 0; m < 8; ++m) att2[(b0 + m) * ATTD + col] = acc[m];
    } else {
      int j = col - ATTD;
      float bv = bb[j];
#pragma unroll
      for (int m = 0; m < 8; ++m) acc[m] = bv;
#pragma unroll 4
      for (int k = 0; k < DECD; ++k) {
        float w = Wb[k * EE + j];
#pragma unroll
        for (int m = 0; m < 8; ++m) acc[m] = fmaf(hp[m * DECD + k], w, acc[m]);
      }
#pragma unroll
      for (int m = 0; m < 8; ++m) gateLin[(b0 + m) * EE + j] = acc[m];
    }
  } else {
    int cidx = idx - 2560 * 8;                    // 0..65535
    int r = cidx & 32767;
    int b = r >> 9, k = r & 511;
    if (cidx < 32768) {
      int cap = caps[sort_ind[b] * LL + t];
      xfull[b * 3072 + k] = emb[(size_t)cap * EMBD + k];
    } else {
      xfull[b * 3072 + 2560 + k] = h_in[b * DECD + k];
    }
  }
}

// e[b,p] = relu(att1[b,p,:] + att2[b,:]) . Wf + bf   (one wave per (b,p))
__global__ __launch_bounds__(256) void k_e(const float* __restrict__ att1,
                                           const float* __restrict__ att2,
                                           const float* __restrict__ Wf,
                                           const float* __restrict__ bf,
                                           float* __restrict__ e) {
  int wave = (blockIdx.x * 256 + threadIdx.x) >> 6;
  int lane = threadIdx.x & 63;
  int b = wave / PP, p = wave - b * PP;
  const float* a1 = att1 + (size_t)(b * PP + p) * ATTD;
  const float* a2 = att2 + b * ATTD;
  float acc = 0.f;
#pragma unroll
  for (int k = lane; k < ATTD; k += 64) {
    float v = a1[k] + a2[k];
    acc = fmaf(fmaxf(v, 0.f), Wf[k], acc);
  }
#pragma unroll
  for (int off = 32; off; off >>= 1) acc += __shfl_xor(acc, off);
  if (lane == 0) e[b * PP + p] = acc + bf[0];
}

// softmax over p (per b), awe = sum_p alpha*enc, gate, write into xfull[:,512:2560]
// grid (b,chunk): 64*4 blocks; chunk covers 512 of E=2048 (float2/thread)
__global__ __launch_bounds__(256) void k_awe(const float* __restrict__ e,
                                             const float* __restrict__ enc,
                                             const int* __restrict__ sort_ind,
                                             const float* __restrict__ gateLin,
                                             const int* __restrict__ dlens,
                                             float* __restrict__ xfull,
                                             float* __restrict__ alphas_out,
                                             int t) {
  int b = blockIdx.x >> 2, c = blockIdx.x & 3;
  int tid = threadIdx.x;
  __shared__ float sa[PP];
  float ev = 0.f;
  if (tid < PP) { ev = e[b * PP + tid]; sa[tid] = ev; }
  __syncthreads();
  float m = -1e30f;
  for (int p = 0; p < PP; ++p) m = fmaxf(m, sa[p]);
  __syncthreads();
  if (tid < PP) sa[tid] = expf(ev - m);
  __syncthreads();
  float s = 0.f;
  for (int p = 0; p < PP; ++p) s += sa[p];
  float inv = 1.0f / s;

  int e0 = (c << 9) + tid * 2;
  int sb = sort_ind[b];
  const float* base = enc + (size_t)sb * PP * EE + e0;
  float ax = 0.f, ay = 0.f;
#pragma unroll 4
  for (int p = 0; p < PP; ++p) {
    float a = sa[p];
    float2 v = *(const float2*)(base + (size_t)p * EE);
    ax = fmaf(a, v.x, ax);
    ay = fmaf(a, v.y, ay);
  }
  ax *= inv; ay *= inv;
  float2 gl = *(const float2*)(gateLin + b * EE + e0);
  float gx = 1.f / (1.f + expf(-gl.x));
  float gy = 1.f / (1.f + expf(-gl.y));
  float* xo = xfull + b * 3072 + EMBD + e0;
  xo[0] = ax * gx;
  xo[1] = ay * gy;
  if (c == 0 && tid < PP) {
    float msk = (t < dlens[b]) ? 1.f : 0.f;
    alphas_out[((size_t)b * TT + t) * PP + tid] = sa[tid] * inv * msk;
  }
}

// g-partials: xfull(64x3072) @ [Wih;Whh](3072x2048), split-K=2, 8 b-rows/thread
__global__ __launch_bounds__(256) void k_gates(const float* __restrict__ xfull,
                                               const float* __restrict__ Wih,
                                               const float* __restrict__ Whh,
                                               float* __restrict__ gpart) {
  int idx = blockIdx.x * 256 + threadIdx.x;      // 2048 cols * 8 bq * 2 ks = 32768
  int col = idx & 2047;
  int bq = (idx >> 11) & 7;
  int ks = idx >> 14;
  int b0 = bq * 8;
  const float* x0 = xfull + b0 * 3072;
  int kstart = ks * 1536, kend = kstart + 1536;
  float acc[8];
#pragma unroll
  for (int m = 0; m < 8; ++m) acc[m] = 0.f;
  int k1 = kend < 2560 ? kend : 2560;
#pragma unroll 4
  for (int k = kstart; k < k1; ++k) {
    float w = Wih[(size_t)k * EE + col];
#pragma unroll
    for (int m = 0; m < 8; ++m) acc[m] = fmaf(x0[m * 3072 + k], w, acc[m]);
  }
  int k2 = kstart > 2560 ? kstart : 2560;
#pragma unroll 4
  for (int k = k2; k < kend; ++k) {
    float w = Whh[(size_t)(k - 2560) * EE + col];
#pragma unroll
    for (int m = 0; m < 8; ++m) acc[m] = fmaf(x0[m * 3072 + k], w, acc[m]);
  }
  float* gp = gpart + (size_t)ks * (BB * EE) + b0 * EE + col;
#pragma unroll
  for (int m = 0; m < 8; ++m) gp[m * EE] = acc[m];
}

__global__ __launch_bounds__(256) void k_cell(const float* __restrict__ gpart,
                                              const float* __restrict__ bih,
                                              const float* __restrict__ bhh,
                                              const float* __restrict__ c_in,
                                              float* __restrict__ h_out,
                                              float* __restrict__ c_out,
                                              float* __restrict__ hn_buf) {
  int idx = blockIdx.x * 256 + threadIdx.x;      // B*DEC = 32768
  int b = idx >> 9, j = idx & 511;
  const float* g0 = gpart + (size_t)b * EE;
  const float* g1 = gpart + (size_t)BB * EE + (size_t)b * EE;
  float gi = g0[j] + g1[j] + bih[j] + bhh[j];
  float gf = g0[j + 512] + g1[j + 512] + bih[j + 512] + bhh[j + 512];
  float gg = g0[j + 1024] + g1[j + 1024] + bih[j + 1024] + bhh[j + 1024];
  float go = g0[j + 1536] + g1[j + 1536] + bih[j + 1536] + bhh[j + 1536];
  float ig = 1.f / (1.f + expf(-gi));
  float fg = 1.f / (1.f + expf(-gf));
  float gt = tanhf(gg);
  float og = 1.f / (1.f + expf(-go));
  float cn = fg * c_in[idx] + ig * gt;
  float hn = og * tanhf(cn);
  h_out[idx] = hn;
  c_out[idx] = cn;
  hn_buf[idx] = hn;
}

// preds = (hn @ Wfc + bfc) * mask ; 8 b-rows per thread
__global__ __launch_bounds__(256) void k_preds(const float* __restrict__ hn,
                                               const float* __restrict__ Wfc,
                                               const float* __restrict__ bfc,
                                               const int* __restrict__ dlens,
                                               float* __restrict__ out,
                                               int t) {
  int col = blockIdx.x * 256 + threadIdx.x;
  if (col >= VV) return;
  int b0 = blockIdx.y * 8;
  const float* hp = hn + b0 * DECD;
  float bv = bfc[col];
  float acc[8];
#pragma unroll
  for (int m = 0; m < 8; ++m) acc[m] = bv;
#pragma unroll 4
  for (int k = 0; k < DECD; ++k) {
    float w = Wfc[(size_t)k * VV + col];
#pragma unroll
    for (int m = 0; m < 8; ++m) acc[m] = fmaf(hp[m * DECD + k], w, acc[m]);
  }
#pragma unroll
  for (int m = 0; m < 8; ++m) {
    float msk = (t < dlens[b0 + m]) ? 1.f : 0.f;
    out[((size_t)(b0 + m) * TT + t) * VV + col] = acc[m] * msk;
  }
}

// ---------------- launch ----------------

extern "C" void kernel_launch(void* const* d_in, const int* in_sizes, int n_in,
                              void* d_out, int out_size, void* d_ws, size_t ws_size,
                              hipStream_t stream) {
  const float* enc  = (const float*)d_in[0];
  const int*   caps = (const int*)d_in[1];
  const int*   clen = (const int*)d_in[2];
  const float* emb  = (const float*)d_in[3];
  const float* We   = (const float*)d_in[4];
  const float* be   = (const float*)d_in[5];
  const float* Wd   = (const float*)d_in[6];
  const float* bd   = (const float*)d_in[7];
  const float* Wf   = (const float*)d_in[8];
  const float* bf   = (const float*)d_in[9];
  const float* Wih  = (const float*)d_in[10];
  const float* bih  = (const float*)d_in[11];
  const float* Whh  = (const float*)d_in[12];
  const float* bhh  = (const float*)d_in[13];
  const float* Wb   = (const float*)d_in[14];
  const float* bb   = (const float*)d_in[15];
  const float* Whi  = (const float*)d_in[16];
  const float* bhi  = (const float*)d_in[17];
  const float* Wci  = (const float*)d_in[18];
  const float* bci  = (const float*)d_in[19];
  const float* Wfc  = (const float*)d_in[20];
  const float* bfc  = (const float*)d_in[21];

  float* ws = (float*)d_ws;
  int* sort_ind = (int*)ws;                      // 64
  int* dlens    = (int*)(ws + 64);               // 64
  float* mean_enc = ws + 128;                    // 64*2048
  float* hbuf0 = ws + 131200;                    // 64*512
  float* hbuf1 = ws + 163968;
  float* cbuf0 = ws + 196736;
  float* cbuf1 = ws + 229504;
  float* hn      = ws + 262272;                  // 64*512
  float* att2    = ws + 295040;                  // 64*512
  float* gateLin = ws + 327808;                  // 64*2048
  float* ebuf    = ws + 458880;                  // 64*196
  float* xfull   = ws + 471424;                  // 64*3072
  float* gpart   = ws + 668032;                  // 2*64*2048
  float* att1    = ws + 930176;                  // 64*196*512
  float* preds_out  = (float*)d_out;
  float* alphas_out = preds_out + (size_t)BB * TT * VV;

  hipLaunchKernelGGL(k_sort, dim3(1), dim3(64), 0, stream, clen, sort_ind, dlens);
  hipLaunchKernelGGL(k_mean, dim3(512), dim3(256), 0, stream, enc, sort_ind, mean_enc);
  hipLaunchKernelGGL(k_h0c0, dim3(256), dim3(256), 0, stream, mean_enc, Whi, bhi, Wci, bci,
                     hbuf0, cbuf0);
  hipLaunchKernelGGL(k_att1, dim3(1568), dim3(256), 0, stream, enc, sort_ind, We, be, att1);

  float* hb[2] = {hbuf0, hbuf1};
  float* cb[2] = {cbuf0, cbuf1};
  for (int t = 0; t < TT; ++t) {
    const float* h_in = hb[t & 1];
    const float* c_in = cb[t & 1];
    float* h_out = hb[(t + 1) & 1];
    float* c_out = cb[(t + 1) & 1];
    hipLaunchKernelGGL(k_hproj, dim3(336), dim3(256), 0, stream,
                       h_in, Wd, bd, Wb, bb, emb, caps, sort_ind, att2, gateLin, xfull, t);
    hipLaunchKernelGGL(k_e, dim3(3136), dim3(256), 0, stream, att1, att2, Wf, bf, ebuf);
    hipLaunchKernelGGL(k_awe, dim3(256), dim3(256), 0, stream,
                       ebuf, enc, sort_ind, gateLin, dlens, xfull, alphas_out, t);
    hipLaunchKernelGGL(k_gates, dim3(128), dim3(256), 0, stream, xfull, Wih, Whh, gpart);
    hipLaunchKernelGGL(k_cell, dim3(128), dim3(256), 0, stream,
                       gpart, bih, bhh, c_in, h_out, c_out, hn);
    hipLaunchKernelGGL(k_preds, dim3(40, 8), dim3(256), 0, stream,
                       hn, Wfc, bfc, dlens, preds_out, t);
  }
}